// Round 2
// baseline (517.971 us; speedup 1.0000x reference)
//
#include <hip/hip_runtime.h>
#include <math.h>

// Problem constants (from reference)
#define B 4
#define H 2
#define L 2048
#define DM 32          // d_model
#define F 16           // feat dim
#define HD 16          // head dim
#define DD 273         // 1 + F + F*F taylor feature dim
#define CHK 64         // chunk length
#define NC (L / CHK)   // 32 chunks
#define BH (B * H)     // 8

#define SC_LIN 0.5f                   // 1/RRD, RRD=2
#define SC_QUAD 0.17677669529663687f  // 1/(RD*sqrt(2)) = 1/(4*sqrt(2))

// ---------------------------------------------------------------------------
// Kernel A: fused QKV projection.
// grid 128 x 256 threads. Each block: 64 rows. Lane = row; each wave computes
// 24 of the 96 output channels for all 64 rows. x row held in registers;
// W reads are wave-uniform -> scalar cache. No LDS.
// ---------------------------------------------------------------------------
__global__ __launch_bounds__(256) void proj_kernel(
    const float* __restrict__ hs, const float* __restrict__ Wq,
    const float* __restrict__ Wk, const float* __restrict__ Wv,
    float* __restrict__ qp, float* __restrict__ kp, float* __restrict__ vp) {
  int lane = threadIdx.x & 63;
  int wave = threadIdx.x >> 6;
  int row = blockIdx.x * 64 + lane;  // b*L + l
  int b = row >> 11, l = row & (L - 1);
  float x[DM];
  const float4* xr = (const float4*)(hs + (size_t)row * DM);
#pragma unroll
  for (int j = 0; j < DM / 4; j++) {
    float4 v = xr[j];
    x[4 * j] = v.x; x[4 * j + 1] = v.y; x[4 * j + 2] = v.z; x[4 * j + 3] = v.w;
  }
  for (int cc = wave * 24; cc < wave * 24 + 24; cc++) {
    int p = cc >> 5, c = cc & 31;
    const float* __restrict__ W = (p == 0) ? Wq : (p == 1) ? Wk : Wv;
    float acc = 0.f;
#pragma unroll
    for (int i = 0; i < DM; i++) acc += x[i] * W[c * DM + i];
    int h = c >> 4, f = c & 15;
    float* dst = (p == 0) ? qp : (p == 1) ? kp : vp;
    dst[(((size_t)(b * H + h) * L) + l) * F + f] = acc;
  }
}

// ---------------------------------------------------------------------------
// Kernel B: per-chunk state sums (raw, not prefixed).
//   S_kv[dd][hd] = sum_{s in chunk} phi(k_s)[dd] * v_s[hd]
//   S_k[dd]      = sum_{s in chunk} phi(k_s)[dd]
// grid BH*NC = 256 blocks x 256 threads; one thread per dd (2 reps).
// ---------------------------------------------------------------------------
__global__ __launch_bounds__(256) void chunksum_kernel(
    const float* __restrict__ kp, const float* __restrict__ vp,
    float* __restrict__ S_kv, float* __restrict__ S_k) {
  int blk = blockIdx.x;  // bh*NC + ch
  int bh = blk >> 5, ch = blk & (NC - 1);
  __shared__ float ks[CHK * F];
  __shared__ float vs[CHK * F];
  const float4* kb = (const float4*)(kp + ((size_t)bh * L + (size_t)ch * CHK) * F);
  const float4* vb = (const float4*)(vp + ((size_t)bh * L + (size_t)ch * CHK) * F);
  ((float4*)ks)[threadIdx.x] = kb[threadIdx.x];  // 64*16/4 = 256 float4
  ((float4*)vs)[threadIdx.x] = vb[threadIdx.x];
  __syncthreads();

#pragma unroll
  for (int rep = 0; rep < 2; rep++) {
    int dd = threadIdx.x + rep * 256;
    if (dd >= DD) break;
    // dd -> (i, j, sc) with sentinel 16 meaning "the constant-1 feature"
    int i, j;
    float sc;
    if (dd == 0) {
      i = 16; j = 16; sc = 1.0f;
    } else if (dd <= F) {
      i = dd - 1; j = 16; sc = SC_LIN;
    } else {
      int m = dd - 17;
      i = m >> 4; j = m & 15; sc = SC_QUAD;
    }
    int ii = (i < 16) ? i : 0;
    int jj = (j < 16) ? j : 0;
    bool iv = (i < 16), jv = (j < 16);
    float acc[HD];
#pragma unroll
    for (int hh = 0; hh < HD; hh++) acc[hh] = 0.f;
    float acck = 0.f;
    for (int p = 0; p < CHK; p++) {
      float a = iv ? ks[p * F + ii] : 1.0f;
      float bb = jv ? ks[p * F + jj] : 1.0f;
      float kf = sc * a * bb;
      acck += kf;
      const float4* vr = (const float4*)(vs + p * F);
#pragma unroll
      for (int h4 = 0; h4 < 4; h4++) {
        float4 v = vr[h4];
        acc[4 * h4] += kf * v.x;
        acc[4 * h4 + 1] += kf * v.y;
        acc[4 * h4 + 2] += kf * v.z;
        acc[4 * h4 + 3] += kf * v.w;
      }
    }
    float* dst = S_kv + ((size_t)blk * DD + dd) * HD;
#pragma unroll
    for (int hh = 0; hh < HD; hh++) dst[hh] = acc[hh];
    S_k[(size_t)blk * DD + dd] = acck;
  }
}

// ---------------------------------------------------------------------------
// Kernel C: element-parallel exclusive prefix over NC chunks per (b,h).
// grid = BH * 19 blocks x 256 threads; one thread per state element.
// Loads hoisted into registers so all NC loads pipeline.
// ---------------------------------------------------------------------------
#define PSLICES 19  // ceil((DD*HD + DD)/256) = ceil(4641/256)
__global__ __launch_bounds__(256) void prefix_kernel(float* __restrict__ S_kv,
                                                     float* __restrict__ S_k) {
  int blk = blockIdx.x;
  int bh = blk / PSLICES, sl = blk % PSLICES;
  int e = sl * 256 + threadIdx.x;
  if (e < DD * HD) {
    size_t base = (size_t)bh * NC * DD * HD + e;
    float v[NC];
#pragma unroll
    for (int c = 0; c < NC; c++) v[c] = S_kv[base + (size_t)c * DD * HD];
    float run = 0.f;
#pragma unroll
    for (int c = 0; c < NC; c++) {
      S_kv[base + (size_t)c * DD * HD] = run;
      run += v[c];
    }
  } else if (e < DD * HD + DD) {
    int e2 = e - DD * HD;
    size_t base = (size_t)bh * NC * DD + e2;
    float v[NC];
#pragma unroll
    for (int c = 0; c < NC; c++) v[c] = S_k[base + (size_t)c * DD];
    float run = 0.f;
#pragma unroll
    for (int c = 0; c < NC; c++) {
      S_k[base + (size_t)c * DD] = run;
      run += v[c];
    }
  }
}

// ---------------------------------------------------------------------------
// Kernel D: per-chunk output, 4-way split per position.
// grid BH*NC = 256 blocks x 256 threads (4 waves). Wave q4 handles feature
// rows i in {q4, q4+4, q4+8, q4+12} of the inter part and intra positions
// s == q4 (mod 4); LDS tree-reduction combines the 4 partial (acc, den).
// State reads are wave-uniform global loads -> scalar pipe.
// ---------------------------------------------------------------------------
template <int Q4>
__device__ inline void inter_part(const float* __restrict__ S,
                                  const float* __restrict__ Sk,
                                  const float* qreg, float* acc, float& den) {
  if (Q4 == 0) {
    den += Sk[0];
#pragma unroll
    for (int hh = 0; hh < HD; hh++) acc[hh] += S[hh];
  }
#pragma unroll
  for (int m = 0; m < 4; m++) {
    const int i = Q4 + m * 4;  // compile-time after unroll
    float qf = qreg[i] * SC_LIN;
    den += qf * Sk[1 + i];
    const float* Sr = S + (1 + i) * HD;
#pragma unroll
    for (int hh = 0; hh < HD; hh++) acc[hh] += qf * Sr[hh];
    float qi = qreg[i] * SC_QUAD;
    const float* Sr2 = S + (17 + i * 16) * HD;
    const float* Skr = Sk + 17 + i * 16;
#pragma unroll
    for (int j = 0; j < F; j++) {
      float qf2 = qi * qreg[j];
      den += qf2 * Skr[j];
#pragma unroll
      for (int hh = 0; hh < HD; hh++) acc[hh] += qf2 * Sr2[j * HD + hh];
    }
  }
}

__global__ __launch_bounds__(256) void outchunk_kernel(
    const float* __restrict__ qp, const float* __restrict__ kp,
    const float* __restrict__ vp, const float* __restrict__ St_kv,
    const float* __restrict__ St_k, float* __restrict__ y) {
  int blk = blockIdx.x;  // bh*NC + ch
  int bh = blk >> 5, ch = blk & (NC - 1);
  int b = bh >> 1, h = bh & 1;
  int t = threadIdx.x & 63;   // position in chunk
  int q4 = threadIdx.x >> 6;  // work-split index (wave)

  __shared__ float ks[CHK * F];
  __shared__ float vs[CHK * F];
  __shared__ float red[4][CHK][20];  // [q4][t][acc0..15, den]

  const float4* kb = (const float4*)(kp + ((size_t)bh * L + (size_t)ch * CHK) * F);
  const float4* vb = (const float4*)(vp + ((size_t)bh * L + (size_t)ch * CHK) * F);
  ((float4*)ks)[threadIdx.x] = kb[threadIdx.x];
  ((float4*)vs)[threadIdx.x] = vb[threadIdx.x];

  // q row for this position, in registers (all 4 waves load their copy)
  float qreg[F];
  const float4* qr = (const float4*)(qp + ((size_t)bh * L + (size_t)ch * CHK + t) * F);
#pragma unroll
  for (int j = 0; j < 4; j++) {
    float4 v = qr[j];
    qreg[4 * j] = v.x; qreg[4 * j + 1] = v.y;
    qreg[4 * j + 2] = v.z; qreg[4 * j + 3] = v.w;
  }
  __syncthreads();

  const float* S = St_kv + (size_t)blk * DD * HD;   // exclusive prefix state
  const float* Sk = St_k + (size_t)blk * DD;

  float acc[HD];
#pragma unroll
  for (int hh = 0; hh < HD; hh++) acc[hh] = 0.f;
  float den = 0.f;

  // ---- inter-chunk part (wave-split by feature row)
  switch (q4) {
    case 0: inter_part<0>(S, Sk, qreg, acc, den); break;
    case 1: inter_part<1>(S, Sk, qreg, acc, den); break;
    case 2: inter_part<2>(S, Sk, qreg, acc, den); break;
    default: inter_part<3>(S, Sk, qreg, acc, den); break;
  }

  // ---- intra-chunk causal part: s = q4 + 4m, closed-form feature dot
#pragma unroll
  for (int m = 0; m < CHK / 4; m++) {
    int s = q4 + 4 * m;
    if (s <= t) {
      float dot = 0.f;
#pragma unroll
      for (int i = 0; i < F; i++) dot += qreg[i] * ks[s * F + i];
      float scv = 1.0f + dot * 0.25f + dot * dot * 0.03125f;
      den += scv;
      const float4* vr = (const float4*)(vs + s * F);
#pragma unroll
      for (int h4 = 0; h4 < 4; h4++) {
        float4 v = vr[h4];
        acc[4 * h4] += scv * v.x;
        acc[4 * h4 + 1] += scv * v.y;
        acc[4 * h4 + 2] += scv * v.z;
        acc[4 * h4 + 3] += scv * v.w;
      }
    }
  }

  // ---- reduce the 4 partials per position
#pragma unroll
  for (int hh = 0; hh < HD; hh++) red[q4][t][hh] = acc[hh];
  red[q4][t][16] = den;
  __syncthreads();

  for (int idx = threadIdx.x; idx < CHK * 17; idx += 256) {
    int t2 = idx / 17, e = idx % 17;
    float s4 = red[0][t2][e] + red[1][t2][e] + red[2][t2][e] + red[3][t2][e];
    red[0][t2][e] = s4;
  }
  __syncthreads();

  if (threadIdx.x < CHK) {
    int t2 = threadIdx.x;
    float inv = 1.0f / (red[0][t2][16] + 1e-12f);
    float* yb = y + (((size_t)(b * L + ch * CHK + t2)) * H + h) * HD;
#pragma unroll
    for (int hh = 0; hh < HD; hh++) yb[hh] = red[0][t2][hh] * inv;
  }
}

// ---------------------------------------------------------------------------
// Kernel E: output projection out = y @ Wo^T. Row in registers, uniform Wo.
// grid 128 x 256: 64 rows/block, wave w computes channels [8w, 8w+8).
// ---------------------------------------------------------------------------
__global__ __launch_bounds__(256) void out_kernel(const float* __restrict__ y,
                                                  const float* __restrict__ Wo,
                                                  float* __restrict__ out) {
  int lane = threadIdx.x & 63;
  int wave = threadIdx.x >> 6;
  int row = blockIdx.x * 64 + lane;
  float yr[DM];
  const float4* yb = (const float4*)(y + (size_t)row * DM);
#pragma unroll
  for (int j = 0; j < DM / 4; j++) {
    float4 v = yb[j];
    yr[4 * j] = v.x; yr[4 * j + 1] = v.y; yr[4 * j + 2] = v.z; yr[4 * j + 3] = v.w;
  }
  for (int c = wave * 8; c < wave * 8 + 8; c++) {
    float acc = 0.f;
#pragma unroll
    for (int i = 0; i < DM; i++) acc += yr[i] * Wo[c * DM + i];
    out[(size_t)row * DM + c] = acc;
  }
}

extern "C" void kernel_launch(void* const* d_in, const int* in_sizes, int n_in,
                              void* d_out, int out_size, void* d_ws,
                              size_t ws_size, hipStream_t stream) {
  const float* hs = (const float*)d_in[0];
  const float* Wq = (const float*)d_in[1];
  const float* Wk = (const float*)d_in[2];
  const float* Wv = (const float*)d_in[3];
  const float* Wo = (const float*)d_in[4];
  float* out = (float*)d_out;

  float* ws = (float*)d_ws;
  float* qp = ws;                                  // BH*L*F      = 262144
  float* kp = qp + (size_t)BH * L * F;             // 262144
  float* vp = kp + (size_t)BH * L * F;             // 262144
  float* S_kv = vp + (size_t)BH * L * F;           // BH*NC*DD*HD = 1118208
  float* S_k = S_kv + (size_t)BH * NC * DD * HD;   // BH*NC*DD    = 69888
  float* y = S_k + (size_t)BH * NC * DD;           // B*L*H*HD    = 262144
  // total ~9 MB fp32 workspace

  proj_kernel<<<B * L / 64, 256, 0, stream>>>(hs, Wq, Wk, Wv, qp, kp, vp);
  chunksum_kernel<<<BH * NC, 256, 0, stream>>>(kp, vp, S_kv, S_k);
  prefix_kernel<<<BH * PSLICES, 256, 0, stream>>>(S_kv, S_k);
  outchunk_kernel<<<BH * NC, 256, 0, stream>>>(qp, kp, vp, S_kv, S_k, y);
  out_kernel<<<B * L / 64, 256, 0, stream>>>(y, Wo, out);
}

// Round 3
// 106.884 us; speedup vs baseline: 4.8461x; 4.8461x over previous
//
#include <hip/hip_runtime.h>
#include <math.h>

// Problem constants (from reference)
#define B 4
#define H 2
#define L 2048
#define DM 32          // d_model
#define F 16           // feat dim
#define HD 16          // head dim
#define DD 273         // 1 + F + F*F taylor feature dim
#define CHK 64         // chunk length
#define NC (L / CHK)   // 32 chunks
#define BH (B * H)     // 8

#define SC_LIN 0.5f                   // 1/RRD, RRD=2
#define SC_QUAD 0.17677669529663687f  // 1/(RD*sqrt(2)) = 1/(4*sqrt(2))

// ---------------------------------------------------------------------------
// Kernel 1: fused projection + per-chunk state sums.
// Block = (bh, ch). Phase 1: project this chunk's q,k,v (head h only):
// 48 channels x 64 rows; lane = row, wave w does channels [12w, 12w+12).
// q,k,v written to global (for outchunk); k,v also kept in LDS.
// Phase 2: thread dd computes S_kv[dd][:] and S_k[dd] over the 64 positions.
// ---------------------------------------------------------------------------
__global__ __launch_bounds__(256) void chunksum_kernel(
    const float* __restrict__ hs, const float* __restrict__ Wq,
    const float* __restrict__ Wk, const float* __restrict__ Wv,
    float* __restrict__ qp, float* __restrict__ kp, float* __restrict__ vp,
    float* __restrict__ S_kv, float* __restrict__ S_k) {
  int blk = blockIdx.x;  // bh*NC + ch
  int bh = blk >> 5, ch = blk & (NC - 1);
  int b = bh >> 1, h = bh & 1;
  int lane = threadIdx.x & 63, wave = threadIdx.x >> 6;
  int l = ch * CHK + lane;

  __shared__ float ks[CHK][F + 1];  // padded; col 16 = 1.0 (sentinel feature)
  __shared__ float vs[CHK][F];

  // ---- phase 1: projection, x row in registers
  float x[DM];
  const float4* xr = (const float4*)(hs + ((size_t)b * L + l) * DM);
#pragma unroll
  for (int j = 0; j < DM / 4; j++) {
    float4 v = xr[j];
    x[4 * j] = v.x; x[4 * j + 1] = v.y; x[4 * j + 2] = v.z; x[4 * j + 3] = v.w;
  }
  for (int c = wave * 12; c < wave * 12 + 12; c++) {
    int kind = c >> 4;  // 0=q, 1=k, 2=v  (uniform per iteration)
    int f = c & 15;
    const float* __restrict__ W = (kind == 0) ? Wq : (kind == 1) ? Wk : Wv;
    const float* wr = W + (size_t)(h * 16 + f) * DM;
    float acc = 0.f;
#pragma unroll
    for (int i = 0; i < DM; i++) acc += x[i] * wr[i];
    float* dst = (kind == 0) ? qp : (kind == 1) ? kp : vp;
    dst[((size_t)bh * L + l) * F + f] = acc;
    if (kind == 1) ks[lane][f] = acc;
    if (kind == 2) vs[lane][f] = acc;
  }
  if (threadIdx.x < CHK) ks[threadIdx.x][16] = 1.0f;
  __syncthreads();

  // ---- phase 2: per-dd sums
#pragma unroll
  for (int rep = 0; rep < 2; rep++) {
    int dd = threadIdx.x + rep * 256;
    if (dd >= DD) break;
    // dd -> (i, j, sc); 16 is the constant-1 sentinel column
    int i, j;
    float sc;
    if (dd == 0) {
      i = 16; j = 16; sc = 1.0f;
    } else if (dd <= F) {
      i = dd - 1; j = 16; sc = SC_LIN;
    } else {
      int m = dd - 17;
      i = m >> 4; j = m & 15; sc = SC_QUAD;
    }
    float acc[HD];
#pragma unroll
    for (int hh = 0; hh < HD; hh++) acc[hh] = 0.f;
    float acck = 0.f;
    for (int p = 0; p < CHK; p++) {
      float kf = sc * ks[p][i] * ks[p][j];
      acck += kf;
      const float4* vr = (const float4*)vs[p];  // broadcast (uniform p)
#pragma unroll
      for (int h4 = 0; h4 < 4; h4++) {
        float4 v = vr[h4];
        acc[4 * h4] += kf * v.x;
        acc[4 * h4 + 1] += kf * v.y;
        acc[4 * h4 + 2] += kf * v.z;
        acc[4 * h4 + 3] += kf * v.w;
      }
    }
    float* dst = S_kv + ((size_t)blk * DD + dd) * HD;
#pragma unroll
    for (int hh = 0; hh < HD; hh++) dst[hh] = acc[hh];
    S_k[(size_t)blk * DD + dd] = acck;
  }
}

// ---------------------------------------------------------------------------
// Kernel 2: element-parallel exclusive prefix over NC chunks per (b,h).
// One thread per state element; loads hoisted so the NC loads pipeline.
// ---------------------------------------------------------------------------
#define PSLICES 19  // ceil((DD*HD + DD)/256)
__global__ __launch_bounds__(256) void prefix_kernel(float* __restrict__ S_kv,
                                                     float* __restrict__ S_k) {
  int blk = blockIdx.x;
  int bh = blk / PSLICES, sl = blk % PSLICES;
  int e = sl * 256 + threadIdx.x;
  if (e < DD * HD) {
    size_t base = (size_t)bh * NC * DD * HD + e;
    float v[NC];
#pragma unroll
    for (int c = 0; c < NC; c++) v[c] = S_kv[base + (size_t)c * DD * HD];
    float run = 0.f;
#pragma unroll
    for (int c = 0; c < NC; c++) {
      S_kv[base + (size_t)c * DD * HD] = run;
      run += v[c];
    }
  } else if (e < DD * HD + DD) {
    int e2 = e - DD * HD;
    size_t base = (size_t)bh * NC * DD + e2;
    float v[NC];
#pragma unroll
    for (int c = 0; c < NC; c++) v[c] = S_k[base + (size_t)c * DD];
    float run = 0.f;
#pragma unroll
    for (int c = 0; c < NC; c++) {
      S_k[base + (size_t)c * DD] = run;
      run += v[c];
    }
  }
}

// ---------------------------------------------------------------------------
// Kernel 3: per-chunk output. Block = (bh, ch), 256 threads; lane = t,
// wave = u. S + Sk staged in LDS (broadcast reads). Inter: wave u walks
// dd = u, u+4, ... (uniform decode branch); per dd: phi from padded qs
// (stride 17 -> 2-way, free) and 4 broadcast b128 reads of the S row.
// Intra: s = u + 4m, masked (no divergence). 4-way LDS reduction at end.
// All per-thread arrays compile-time indexed -> no scratch.
// ---------------------------------------------------------------------------
__global__ __launch_bounds__(256) void outchunk_kernel(
    const float* __restrict__ qp, const float* __restrict__ kp,
    const float* __restrict__ vp, const float* __restrict__ St_kv,
    const float* __restrict__ St_k, float* __restrict__ y) {
  int blk = blockIdx.x;  // bh*NC + ch
  int bh = blk >> 5, ch = blk & (NC - 1);
  int b = bh >> 1, h = bh & 1;
  int t = threadIdx.x & 63;   // position in chunk
  int u = threadIdx.x >> 6;   // wave = work-split index

  __shared__ float qs[CHK][F + 1];  // padded, col 16 = 1.0
  __shared__ float ks[CHK][F];
  __shared__ float vs[CHK][F];
  __shared__ float S[DD][HD];
  __shared__ float Sk[DD + 3];
  __shared__ float red[4][CHK][20];

  const float4* qb = (const float4*)(qp + ((size_t)bh * L + (size_t)ch * CHK) * F);
  const float4* kb = (const float4*)(kp + ((size_t)bh * L + (size_t)ch * CHK) * F);
  const float4* vb = (const float4*)(vp + ((size_t)bh * L + (size_t)ch * CHK) * F);
  {
    int r = threadIdx.x >> 2, c4 = (threadIdx.x & 3) * 4;
    float4 v = qb[threadIdx.x];
    qs[r][c4] = v.x; qs[r][c4 + 1] = v.y; qs[r][c4 + 2] = v.z; qs[r][c4 + 3] = v.w;
    ((float4*)ks)[threadIdx.x] = kb[threadIdx.x];
    ((float4*)vs)[threadIdx.x] = vb[threadIdx.x];
  }
  if (threadIdx.x < CHK) qs[threadIdx.x][16] = 1.0f;
  const float4* Sb = (const float4*)(St_kv + (size_t)blk * DD * HD);
  for (int i = threadIdx.x; i < DD * HD / 4; i += 256) ((float4*)S)[i] = Sb[i];
  const float* Skb = St_k + (size_t)blk * DD;
  for (int i = threadIdx.x; i < DD; i += 256) Sk[i] = Skb[i];

  // q row for this lane's position, in registers
  float qreg[F];
  const float4* qrow = (const float4*)(qp + ((size_t)bh * L + (size_t)ch * CHK + t) * F);
#pragma unroll
  for (int j = 0; j < 4; j++) {
    float4 v = qrow[j];
    qreg[4 * j] = v.x; qreg[4 * j + 1] = v.y;
    qreg[4 * j + 2] = v.z; qreg[4 * j + 3] = v.w;
  }
  __syncthreads();

  float acc[HD];
#pragma unroll
  for (int hh = 0; hh < HD; hh++) acc[hh] = 0.f;
  float den = 0.f;

  // ---- inter-chunk: dd = u mod 4 (uniform within wave)
  for (int dd = u; dd < DD; dd += 4) {
    float phi;
    if (dd == 0) {
      phi = 1.0f;
    } else if (dd <= F) {
      phi = qs[t][dd - 1] * SC_LIN;
    } else {
      int m = dd - 17;
      phi = qs[t][m >> 4] * qs[t][m & 15] * SC_QUAD;
    }
    den += phi * Sk[dd];
    const float4* Sr = (const float4*)S[dd];  // broadcast
#pragma unroll
    for (int j4 = 0; j4 < 4; j4++) {
      float4 sv = Sr[j4];
      acc[4 * j4] += phi * sv.x;
      acc[4 * j4 + 1] += phi * sv.y;
      acc[4 * j4 + 2] += phi * sv.z;
      acc[4 * j4 + 3] += phi * sv.w;
    }
  }

  // ---- intra-chunk causal: s = u + 4m, closed-form feature dot, masked
#pragma unroll
  for (int m = 0; m < CHK / 4; m++) {
    int s = u + 4 * m;
    const float4* kr = (const float4*)ks[s];  // broadcast
    float dot = 0.f;
#pragma unroll
    for (int i4 = 0; i4 < 4; i4++) {
      float4 kv = kr[i4];
      dot += qreg[4 * i4] * kv.x + qreg[4 * i4 + 1] * kv.y +
             qreg[4 * i4 + 2] * kv.z + qreg[4 * i4 + 3] * kv.w;
    }
    float scv = 1.0f + dot * 0.25f + dot * dot * 0.03125f;
    scv = (s <= t) ? scv : 0.0f;
    den += scv;
    const float4* vr = (const float4*)vs[s];  // broadcast
#pragma unroll
    for (int h4 = 0; h4 < 4; h4++) {
      float4 v = vr[h4];
      acc[4 * h4] += scv * v.x;
      acc[4 * h4 + 1] += scv * v.y;
      acc[4 * h4 + 2] += scv * v.z;
      acc[4 * h4 + 3] += scv * v.w;
    }
  }

  // ---- reduce the 4 wave-partials per position
#pragma unroll
  for (int hh = 0; hh < HD; hh++) red[u][t][hh] = acc[hh];
  red[u][t][16] = den;
  __syncthreads();

  for (int idx = threadIdx.x; idx < CHK * 17; idx += 256) {
    int t2 = idx / 17, e = idx % 17;
    red[0][t2][e] =
        red[0][t2][e] + red[1][t2][e] + red[2][t2][e] + red[3][t2][e];
  }
  __syncthreads();

  if (threadIdx.x < CHK) {
    int t2 = threadIdx.x;
    float inv = 1.0f / (red[0][t2][16] + 1e-12f);
    float* yb = y + (((size_t)(b * L + ch * CHK + t2)) * H + h) * HD;
#pragma unroll
    for (int hh = 0; hh < HD; hh++) yb[hh] = red[0][t2][hh] * inv;
  }
}

// ---------------------------------------------------------------------------
// Kernel 4: output projection out = y @ Wo^T. Row in registers, uniform Wo.
// ---------------------------------------------------------------------------
__global__ __launch_bounds__(256) void out_kernel(const float* __restrict__ y,
                                                  const float* __restrict__ Wo,
                                                  float* __restrict__ out) {
  int lane = threadIdx.x & 63;
  int wave = threadIdx.x >> 6;
  int row = blockIdx.x * 64 + lane;
  float yr[DM];
  const float4* yb = (const float4*)(y + (size_t)row * DM);
#pragma unroll
  for (int j = 0; j < DM / 4; j++) {
    float4 v = yb[j];
    yr[4 * j] = v.x; yr[4 * j + 1] = v.y; yr[4 * j + 2] = v.z; yr[4 * j + 3] = v.w;
  }
  for (int c = wave * 8; c < wave * 8 + 8; c++) {
    float acc = 0.f;
#pragma unroll
    for (int i = 0; i < DM; i++) acc += yr[i] * Wo[c * DM + i];
    out[(size_t)row * DM + c] = acc;
  }
}

extern "C" void kernel_launch(void* const* d_in, const int* in_sizes, int n_in,
                              void* d_out, int out_size, void* d_ws,
                              size_t ws_size, hipStream_t stream) {
  const float* hs = (const float*)d_in[0];
  const float* Wq = (const float*)d_in[1];
  const float* Wk = (const float*)d_in[2];
  const float* Wv = (const float*)d_in[3];
  const float* Wo = (const float*)d_in[4];
  float* out = (float*)d_out;

  float* ws = (float*)d_ws;
  float* qp = ws;                                 // BH*L*F      = 262144
  float* kp = qp + (size_t)BH * L * F;            // 262144
  float* vp = kp + (size_t)BH * L * F;            // 262144
  float* S_kv = vp + (size_t)BH * L * F;          // BH*NC*DD*HD = 1118208
  float* S_k = S_kv + (size_t)BH * NC * DD * HD;  // BH*NC*DD    = 69888
  float* y = S_k + (size_t)BH * NC * DD;          // B*L*H*HD    = 262144
  // total ~9 MB fp32 workspace

  chunksum_kernel<<<BH * NC, 256, 0, stream>>>(hs, Wq, Wk, Wv, qp, kp, vp,
                                               S_kv, S_k);
  prefix_kernel<<<BH * PSLICES, 256, 0, stream>>>(S_kv, S_k);
  outchunk_kernel<<<BH * NC, 256, 0, stream>>>(qp, kp, vp, S_kv, S_k, y);
  out_kernel<<<B * L / 64, 256, 0, stream>>>(y, Wo, out);
}

// Round 4
// 106.496 us; speedup vs baseline: 4.8638x; 1.0036x over previous
//
#include <hip/hip_runtime.h>
#include <math.h>

// Problem constants (from reference)
#define B 4
#define H 2
#define L 2048
#define DM 32          // d_model
#define F 16           // feat dim
#define HD 16          // head dim
#define DD 273         // 1 + F + F*F taylor feature dim
#define CHK 64         // chunk length
#define NC (L / CHK)   // 32 chunks
#define BH (B * H)     // 8

#define SC_LIN 0.5f                   // 1/RRD, RRD=2
#define SC_QUAD 0.17677669529663687f  // 1/(RD*sqrt(2)) = 1/(4*sqrt(2))

// ---------------------------------------------------------------------------
// Kernel 1: QKV projection. grid 256 = (row-group 0..127) x (channel-half).
// lane = row (64 rows/block); wave (readfirstlane -> SGPR) picks 12 channels
// of its half. W rows are wave-uniform -> scalar (SMEM) loads. No LDS.
// ---------------------------------------------------------------------------
__global__ __launch_bounds__(256) void proj_kernel(
    const float* __restrict__ hs, const float* __restrict__ Wq,
    const float* __restrict__ Wk, const float* __restrict__ Wv,
    float* __restrict__ qp, float* __restrict__ kp, float* __restrict__ vp) {
  int lane = threadIdx.x & 63;
  int wave = __builtin_amdgcn_readfirstlane(threadIdx.x >> 6);
  int rg = blockIdx.x >> 1;   // 128 row groups
  int half = blockIdx.x & 1;  // channel half (48 channels each)
  int row = rg * 64 + lane;   // b*L + l
  int b = row >> 11, l = row & (L - 1);

  float x[DM];
  const float4* xr = (const float4*)(hs + (size_t)row * DM);
#pragma unroll
  for (int j = 0; j < DM / 4; j++) {
    float4 v = xr[j];
    x[4 * j] = v.x; x[4 * j + 1] = v.y; x[4 * j + 2] = v.z; x[4 * j + 3] = v.w;
  }
  int c0 = half * 48 + wave * 12;
  for (int c = c0; c < c0 + 12; c++) {  // c uniform per iteration
    int kind = c >> 5;                  // 0=q 1=k 2=v
    int cc = c & 31;                    // h*16+f
    const float* __restrict__ W = (kind == 0) ? Wq : (kind == 1) ? Wk : Wv;
    const float* __restrict__ wr = W + (size_t)cc * DM;  // uniform -> s_load
    float acc = 0.f;
#pragma unroll
    for (int i = 0; i < DM; i++) acc += x[i] * wr[i];
    int h = cc >> 4, f = cc & 15;
    float* dst = (kind == 0) ? qp : (kind == 1) ? kp : vp;
    dst[(((size_t)(b * H + h) * L) + l) * F + f] = acc;
  }
}

// ---------------------------------------------------------------------------
// Kernel 2: per-chunk state sums. Block = (bh, ch), 256 threads.
// k chunk staged in LDS (divergent (i,j) reads, conflict-light); v rows read
// with wave-uniform addresses from global (kernel-input, __restrict__, no
// aliasing stores -> SMEM s_load). Thread dd accumulates S_kv[dd][:], S_k[dd].
// ---------------------------------------------------------------------------
__global__ __launch_bounds__(256) void chunksum_kernel(
    const float* __restrict__ kp, const float* __restrict__ vp,
    float* __restrict__ S_kv, float* __restrict__ S_k) {
  int blk = blockIdx.x;  // bh*NC + ch
  int bh = blk >> 5, ch = blk & (NC - 1);
  __shared__ float ks[CHK][F + 1];  // padded; col 16 = 1.0 sentinel

  const float4* kb = (const float4*)(kp + ((size_t)bh * L + (size_t)ch * CHK) * F);
  {
    int r = threadIdx.x >> 2, c4 = (threadIdx.x & 3) * 4;
    float4 v = kb[threadIdx.x];
    ks[r][c4] = v.x; ks[r][c4 + 1] = v.y; ks[r][c4 + 2] = v.z; ks[r][c4 + 3] = v.w;
  }
  if (threadIdx.x < CHK) ks[threadIdx.x][16] = 1.0f;
  __syncthreads();

  const float* __restrict__ vbase = vp + ((size_t)bh * L + (size_t)ch * CHK) * F;

#pragma unroll
  for (int rep = 0; rep < 2; rep++) {
    int dd = threadIdx.x + rep * 256;
    if (dd >= DD) break;
    int i, j;
    float sc;
    if (dd == 0) {
      i = 16; j = 16; sc = 1.0f;
    } else if (dd <= F) {
      i = dd - 1; j = 16; sc = SC_LIN;
    } else {
      int m = dd - 17;
      i = m >> 4; j = m & 15; sc = SC_QUAD;
    }
    float acc[HD];
#pragma unroll
    for (int hh = 0; hh < HD; hh++) acc[hh] = 0.f;
    float acck = 0.f;
    for (int p = 0; p < CHK; p++) {
      float kf = sc * ks[p][i] * ks[p][j];
      acck += kf;
      const float* __restrict__ vr = vbase + p * F;  // uniform -> s_load
#pragma unroll
      for (int hh = 0; hh < HD; hh++) acc[hh] += kf * vr[hh];
    }
    float* dst = S_kv + ((size_t)blk * DD + dd) * HD;
#pragma unroll
    for (int hh = 0; hh < HD; hh++) dst[hh] = acc[hh];
    S_k[(size_t)blk * DD + dd] = acck;
  }
}

// ---------------------------------------------------------------------------
// Kernel 3: element-parallel exclusive prefix over NC chunks per (b,h).
// ---------------------------------------------------------------------------
#define PSLICES 19  // ceil((DD*HD + DD)/256)
__global__ __launch_bounds__(256) void prefix_kernel(float* __restrict__ S_kv,
                                                     float* __restrict__ S_k) {
  int blk = blockIdx.x;
  int bh = blk / PSLICES, sl = blk % PSLICES;
  int e = sl * 256 + threadIdx.x;
  if (e < DD * HD) {
    size_t base = (size_t)bh * NC * DD * HD + e;
    float v[NC];
#pragma unroll
    for (int c = 0; c < NC; c++) v[c] = S_kv[base + (size_t)c * DD * HD];
    float run = 0.f;
#pragma unroll
    for (int c = 0; c < NC; c++) {
      S_kv[base + (size_t)c * DD * HD] = run;
      run += v[c];
    }
  } else if (e < DD * HD + DD) {
    int e2 = e - DD * HD;
    size_t base = (size_t)bh * NC * DD + e2;
    float v[NC];
#pragma unroll
    for (int c = 0; c < NC; c++) v[c] = S_k[base + (size_t)c * DD];
    float run = 0.f;
#pragma unroll
    for (int c = 0; c < NC; c++) {
      S_k[base + (size_t)c * DD] = run;
      run += v[c];
    }
  }
}

// ---------------------------------------------------------------------------
// Kernel 4: per-chunk output. Block = (bh, ch), 512 threads = 8 waves
// (2 waves/SIMD for latency hiding). lane = position t; wave u (SGPR via
// readfirstlane) owns dd = u (mod 8) of the inter sum and s = u (mod 8) of
// the intra sum. All state/k/v rows are wave-uniform loads (scalar pipe);
// LDS only holds q (for phi operands) and the 8-way reduction buffer.
// ---------------------------------------------------------------------------
__global__ __launch_bounds__(512) void outchunk_kernel(
    const float* __restrict__ qp, const float* __restrict__ kp,
    const float* __restrict__ vp, const float* __restrict__ St_kv,
    const float* __restrict__ St_k, float* __restrict__ y) {
  int blk = blockIdx.x;  // bh*NC + ch
  int bh = blk >> 5, ch = blk & (NC - 1);
  int b = bh >> 1, h = bh & 1;
  int t = threadIdx.x & 63;
  int u = __builtin_amdgcn_readfirstlane(threadIdx.x >> 6);  // 0..7

  __shared__ float qs[CHK][F + 1];   // padded, col 16 = 1.0
  __shared__ float red[8][CHK][21];  // pad 21 -> odd stride, conflict-free

  if (threadIdx.x < 256) {
    const float4* qb =
        (const float4*)(qp + ((size_t)bh * L + (size_t)ch * CHK) * F);
    int r = threadIdx.x >> 2, c4 = (threadIdx.x & 3) * 4;
    float4 v = qb[threadIdx.x];
    qs[r][c4] = v.x; qs[r][c4 + 1] = v.y; qs[r][c4 + 2] = v.z; qs[r][c4 + 3] = v.w;
    if (threadIdx.x < CHK) qs[threadIdx.x][16] = 1.0f;
  }

  float qreg[F];
  const float4* qrow =
      (const float4*)(qp + ((size_t)bh * L + (size_t)ch * CHK + t) * F);
#pragma unroll
  for (int j = 0; j < 4; j++) {
    float4 v = qrow[j];
    qreg[4 * j] = v.x; qreg[4 * j + 1] = v.y;
    qreg[4 * j + 2] = v.z; qreg[4 * j + 3] = v.w;
  }
  __syncthreads();

  float acc[HD];
#pragma unroll
  for (int hh = 0; hh < HD; hh++) acc[hh] = 0.f;
  float den = 0.f;

  const float* __restrict__ Sbase = St_kv + (size_t)blk * DD * HD;
  const float* __restrict__ Skb = St_k + (size_t)blk * DD;

  // ---- inter-chunk: dd = u + 8m (uniform per wave -> scalar loads)
  for (int m = 0; m < 35; m++) {
    int dd = u + (m << 3);
    if (dd >= DD) break;  // wave-uniform guard
    float phi;
    if (dd == 0) {
      phi = 1.0f;
    } else if (dd <= F) {
      phi = qs[t][dd - 1] * SC_LIN;
    } else {
      int mm = dd - 17;
      phi = qs[t][mm >> 4] * qs[t][mm & 15] * SC_QUAD;
    }
    den += phi * Skb[dd];
    const float* __restrict__ Sr = Sbase + dd * HD;  // uniform -> s_load
#pragma unroll
    for (int jj = 0; jj < HD; jj++) acc[jj] += phi * Sr[jj];
  }

  // ---- intra-chunk causal: s = u + 8m, closed-form score, masked
  const float* __restrict__ kbase = kp + ((size_t)bh * L + (size_t)ch * CHK) * F;
  const float* __restrict__ vbase = vp + ((size_t)bh * L + (size_t)ch * CHK) * F;
#pragma unroll
  for (int mm = 0; mm < CHK / 8; mm++) {
    int s = u + mm * 8;
    const float* __restrict__ kr = kbase + s * F;  // uniform -> s_load
    float dot = 0.f;
#pragma unroll
    for (int i = 0; i < F; i++) dot += qreg[i] * kr[i];
    float scv = 1.0f + dot * 0.25f + dot * dot * 0.03125f;
    scv = (s <= t) ? scv : 0.0f;
    den += scv;
    const float* __restrict__ vr = vbase + s * F;  // uniform -> s_load
#pragma unroll
    for (int hh = 0; hh < HD; hh++) acc[hh] += scv * vr[hh];
  }

  // ---- 8-way reduction per position
#pragma unroll
  for (int hh = 0; hh < HD; hh++) red[u][t][hh] = acc[hh];
  red[u][t][16] = den;
  __syncthreads();

  for (int idx = threadIdx.x; idx < CHK * 17; idx += 512) {
    int t2 = idx / 17, e = idx % 17;
    float sum = 0.f;
#pragma unroll
    for (int w = 0; w < 8; w++) sum += red[w][t2][e];
    red[0][t2][e] = sum;
  }
  __syncthreads();

  if (threadIdx.x < CHK) {
    int t2 = threadIdx.x;
    float inv = 1.0f / (red[0][t2][16] + 1e-12f);
    float* yb = y + (((size_t)(b * L + ch * CHK + t2)) * H + h) * HD;
#pragma unroll
    for (int hh = 0; hh < HD; hh++) yb[hh] = red[0][t2][hh] * inv;
  }
}

// ---------------------------------------------------------------------------
// Kernel 5: output projection out = y @ Wo^T. Row in regs, uniform Wo rows.
// ---------------------------------------------------------------------------
__global__ __launch_bounds__(256) void out_kernel(const float* __restrict__ y,
                                                  const float* __restrict__ Wo,
                                                  float* __restrict__ out) {
  int lane = threadIdx.x & 63;
  int wave = __builtin_amdgcn_readfirstlane(threadIdx.x >> 6);
  int row = blockIdx.x * 64 + lane;
  float yr[DM];
  const float4* yb = (const float4*)(y + (size_t)row * DM);
#pragma unroll
  for (int j = 0; j < DM / 4; j++) {
    float4 v = yb[j];
    yr[4 * j] = v.x; yr[4 * j + 1] = v.y; yr[4 * j + 2] = v.z; yr[4 * j + 3] = v.w;
  }
  for (int c = wave * 8; c < wave * 8 + 8; c++) {  // uniform
    const float* __restrict__ wr = Wo + (size_t)c * DM;
    float acc = 0.f;
#pragma unroll
    for (int i = 0; i < DM; i++) acc += yr[i] * wr[i];
    out[(size_t)row * DM + c] = acc;
  }
}

extern "C" void kernel_launch(void* const* d_in, const int* in_sizes, int n_in,
                              void* d_out, int out_size, void* d_ws,
                              size_t ws_size, hipStream_t stream) {
  const float* hs = (const float*)d_in[0];
  const float* Wq = (const float*)d_in[1];
  const float* Wk = (const float*)d_in[2];
  const float* Wv = (const float*)d_in[3];
  const float* Wo = (const float*)d_in[4];
  float* out = (float*)d_out;

  float* ws = (float*)d_ws;
  float* qp = ws;                                 // BH*L*F      = 262144
  float* kp = qp + (size_t)BH * L * F;            // 262144
  float* vp = kp + (size_t)BH * L * F;            // 262144
  float* S_kv = vp + (size_t)BH * L * F;          // BH*NC*DD*HD = 1118208
  float* S_k = S_kv + (size_t)BH * NC * DD * HD;  // BH*NC*DD    = 69888
  float* y = S_k + (size_t)BH * NC * DD;          // B*L*H*HD    = 262144
  // total ~9 MB fp32 workspace

  proj_kernel<<<256, 256, 0, stream>>>(hs, Wq, Wk, Wv, qp, kp, vp);
  chunksum_kernel<<<BH * NC, 256, 0, stream>>>(kp, vp, S_kv, S_k);
  prefix_kernel<<<BH * PSLICES, 256, 0, stream>>>(S_kv, S_k);
  outchunk_kernel<<<BH * NC, 512, 0, stream>>>(qp, kp, vp, S_kv, S_k, y);
  out_kernel<<<B * L / 64, 256, 0, stream>>>(y, Wo, out);
}